// Round 2
// baseline (45391.055 us; speedup 1.0000x reference)
//
#include <hip/hip_runtime.h>
#include <hip/hip_bf16.h>

// Leaky 2-layer CTRNN, B=64 T=512 D_IN=256 H=1024 D_OUT=256, alpha=0.1.
// Round 4: round 3 (register-tiled persistent kernel) + __launch_bounds__(512,2).
//  Round 3 SPILLED: default launch_bounds(512) capped the allocator at 128
//  VGPRs; the 4h x 8b v2f acc tile (64 regs) + 16 w-regs + addresses didn't
//  fit -> scratch spill -> WRITE_SIZE 267MB -> 50GB, FETCH 1.3GB -> 75GB,
//  VALUBusy halved, 2x slower. We run exactly 8 waves/CU (1 block, forced by
//  dyn-LDS), i.e. 2 waves/EU, so declaring (512,2) legally unlocks 256
//  VGPRs/wave and the live set fits with pipelining headroom.
//  Everything else identical to round 3:
//   - thread tile = 4h x 8b over a 32-wide interleaved k-slice
//   - LDS w-reads per CU per phase: 512 b128 (8x reg reuse vs round 2)
//   - fr global loads: 1024 dwordx4, 512B-contiguous per wave
//   - w rows XOR-swizzled (c16 ^ ((c16>>3)&7)): measured ~0 bank conflicts
//   - partials: in-wave fold (__shfl_xor 1) + [512][17] LDS scatter/gather
//   - owner mapping (h=tid&7, b=tid>>3), v-carry, agent-relaxed tree barrier
//     unchanged from round 2.

using v2f = __attribute__((ext_vector_type(2))) float;

constexpr int Bsz = 64, Tlen = 512, DIN = 256, Hdim = 1024, DOUT = 256;
constexpr int NBLK = 256;           // persistent, 1 per CU
constexpr int NTHR = 512;           // 8 waves
constexpr int CH = 8;               // h rows per block
constexpr int TH = Tlen * Hdim;     // per-batch state stride (floats)
constexpr int PROW = 17;            // partial-buffer row stride (odd: bank-clean)

__device__ __forceinline__ void gbarrier(unsigned* bar, unsigned phase) {
  __builtin_amdgcn_s_waitcnt(0);            // every thread drains its sc1 stores
  __syncthreads();
  if (threadIdx.x == 0) {
    unsigned* leaf = bar + 32 + (blockIdx.x & 31) * 32;   // 128B-padded leaves
    unsigned old = __hip_atomic_fetch_add(leaf, 1u, __ATOMIC_RELAXED,
                                          __HIP_MEMORY_SCOPE_AGENT);
    if ((old & 7u) == 7u)                   // 8th arrival at this leaf this phase
      __hip_atomic_fetch_add(bar, 1u, __ATOMIC_RELAXED, __HIP_MEMORY_SCOPE_AGENT);
    while (__hip_atomic_load(bar, __ATOMIC_RELAXED, __HIP_MEMORY_SCOPE_AGENT) <
           phase * 32u)
      __builtin_amdgcn_s_sleep(4);
    __builtin_amdgcn_fence(__ATOMIC_ACQUIRE, "agent");  // one buffer_inv
  }
  __syncthreads();
}

// Register-tiled partial dot: rows {wbase row 0..3} x batches {frb + bi*TH},
// k in {4*ks + 128*j + 0..3 : j=0..7}.  acc[hi][bi] accumulates v2f pairs.
__device__ __forceinline__ void dot_tile(const float* __restrict__ wbase,
                                         const float* __restrict__ frb,
                                         int ks, v2f (&acc)[4][8]) {
#pragma unroll
  for (int j = 0; j < 8; ++j) {
    const int c16 = ks + 32 * j;
    const int phys = c16 ^ ((c16 >> 3) & 7);       // matches staging swizzle
    const float* wp = wbase + phys * 4;
    const float4 w0 = *(const float4*)(wp);
    const float4 w1 = *(const float4*)(wp + 1024);
    const float4 w2 = *(const float4*)(wp + 2048);
    const float4 w3 = *(const float4*)(wp + 3072);
    const float* fp = frb + 4 * ks + 128 * j;
#pragma unroll
    for (int bi = 0; bi < 8; ++bi) {
      const float4 f = *(const float4*)(fp + (size_t)bi * TH);
      const v2f fxy = {f.x, f.y}, fzw = {f.z, f.w};
      acc[0][bi] = __builtin_elementwise_fma((v2f){w0.x, w0.y}, fxy, acc[0][bi]);
      acc[0][bi] = __builtin_elementwise_fma((v2f){w0.z, w0.w}, fzw, acc[0][bi]);
      acc[1][bi] = __builtin_elementwise_fma((v2f){w1.x, w1.y}, fxy, acc[1][bi]);
      acc[1][bi] = __builtin_elementwise_fma((v2f){w1.z, w1.w}, fzw, acc[1][bi]);
      acc[2][bi] = __builtin_elementwise_fma((v2f){w2.x, w2.y}, fxy, acc[2][bi]);
      acc[2][bi] = __builtin_elementwise_fma((v2f){w2.z, w2.w}, fzw, acc[2][bi]);
      acc[3][bi] = __builtin_elementwise_fma((v2f){w3.x, w3.y}, fxy, acc[3][bi]);
      acc[3][bi] = __builtin_elementwise_fma((v2f){w3.z, w3.w}, fzw, acc[3][bi]);
    }
  }
}

// fold ks-pairs in-wave (DPP quad-perm), scatter folded partials to LDS.
__device__ __forceinline__ void fold_scatter(v2f (&acc)[4][8], float* __restrict__ smP,
                                             int ks, int hp, int bp) {
  const bool wr = (ks & 1) == 0;
  const int col = ks >> 1;
#pragma unroll
  for (int hi = 0; hi < 4; ++hi) {
#pragma unroll
    for (int bi = 0; bi < 8; ++bi) {
      float s = acc[hi][bi].x + acc[hi][bi].y;
      s += __shfl_xor(s, 1);
      if (wr)
        smP[((8 * bp + bi) * 8 + 4 * hp + hi) * PROW + col] = s;
    }
  }
}

__device__ __forceinline__ float gather16(const float* __restrict__ prow) {
  float s0 = 0.f, s1 = 0.f, s2 = 0.f, s3 = 0.f;
#pragma unroll
  for (int c4 = 0; c4 < 16; c4 += 4) {
    s0 += prow[c4 + 0]; s1 += prow[c4 + 1];
    s2 += prow[c4 + 2]; s3 += prow[c4 + 3];
  }
  return (s0 + s1) + (s2 + s3);
}

__global__ void __launch_bounds__(NTHR, 2)
rnn_recurrent(const float* __restrict__ Wrec0, const float* __restrict__ Wrec1,
              const float* __restrict__ Win1,  const float* __restrict__ b1,
              const __hip_bfloat16* __restrict__ X0,
              float* __restrict__ states0, float* __restrict__ states1,
              unsigned* __restrict__ bar) {
  extern __shared__ float smW[];  // [nrows][1024] swizzled w, then [512][17] partials
  const int bid = blockIdx.x, tid = threadIdx.x;
  const bool isL1 = bid >= NBLK / 2;
  const int c = bid & (NBLK / 2 - 1);       // h chunk 0..127

  // ---- stage weights (swizzled by 16B chunk) ----
  const int nrows = isL1 ? 2 * CH : CH;
  for (int e = tid; e < nrows * 256; e += NTHR) {
    const int r = e >> 8, c16 = e & 255;
    const int phys = c16 ^ ((c16 >> 3) & 7);
    const float* src;
    if (!isL1)      src = Wrec0 + (size_t)(c * CH + r) * Hdim;
    else if (r < CH) src = Wrec1 + (size_t)(c * CH + r) * Hdim;
    else             src = Win1 + (size_t)(c * CH + r - CH) * Hdim;
    *(float4*)(smW + r * 1024 + phys * 4) = *(const float4*)(src + c16 * 4);
  }
  float* smP = smW + nrows * 1024;

  // ---- compute-role coords: thread tile = rows {4hp..4hp+3} x b {8bp..8bp+7},
  //      k-slice ks (32-wide, interleaved) ----
  const int ks = tid & 31, hp = (tid >> 5) & 1, bp = tid >> 6;
  const float* wA = smW + (4 * hp) * 1024;          // rec rows
  const float* wB = smW + (CH + 4 * hp) * 1024;     // in rows (L1)
  const float* recS = (isL1 ? states1 : states0) + (size_t)(8 * bp) * TH;
  const float* inS  = states0 + (size_t)(8 * bp) * TH;

  // ---- owner-role coords: thread owns output (h_off, b), idx == tid ----
  const int h_off = tid & 7, b = tid >> 3;
  const int h = c * CH + h_off;
  const float bias1 = isL1 ? b1[h] : 0.f;
  float* wr = (isL1 ? states1 : states0) + (size_t)b * TH + h;
  const __hip_bfloat16* x0p = X0 + (size_t)b * TH + h;
  const float* prow = smP + tid * PROW;
  float v = 0.f;
  __syncthreads();

  unsigned phase = 1;
  for (int p = 0; p <= Tlen; ++p) {
    // ---- scatter phase ----
    if (!isL1) {
      if (p > 0 && p < Tlen) {
        v2f acc[4][8] = {};
        dot_tile(wA, recS + (size_t)(p - 1) * Hdim, ks, acc);
        fold_scatter(acc, smP, ks, hp, bp);
      }
    } else if (p >= 1) {
      const int t = p - 1;
      v2f acc[4][8] = {};
      if (t > 0) dot_tile(wA, recS + (size_t)(t - 1) * Hdim, ks, acc);
      dot_tile(wB, inS + (size_t)t * Hdim, ks, acc);
      fold_scatter(acc, smP, ks, hp, bp);
    }
    __syncthreads();
    // ---- gather + v update + store ----
    if (!isL1) {
      if (p < Tlen) {
        const float dotv = (p > 0) ? gather16(prow) : 0.f;
        const float accv = __bfloat162float(x0p[(size_t)p * Hdim]) + dotv;
        v = 0.9f * v + 0.1f * accv;
        __hip_atomic_store(wr + (size_t)p * Hdim, fmaxf(v, 0.f),
                           __ATOMIC_RELAXED, __HIP_MEMORY_SCOPE_AGENT);
      }
    } else if (p >= 1) {
      const int t = p - 1;
      const float accv = bias1 + gather16(prow);
      v = 0.9f * v + 0.1f * accv;
      __hip_atomic_store(wr + (size_t)t * Hdim, fmaxf(v, 0.f),
                         __ATOMIC_RELAXED, __HIP_MEMORY_SCOPE_AGENT);
    }
    if (p < Tlen) { gbarrier(bar, phase); ++phase; }
  }
}

// C[n,m] = sum_k A[n,k]*Bm[m,k] + bias[m]; 64x64 tile, fp32, out fp32 or bf16
template <bool OUT_BF16>
__global__ void __launch_bounds__(256)
gemm_nt(const float* __restrict__ A, const float* __restrict__ Bm,
        const float* __restrict__ bias, void* __restrict__ Cout,
        int N, int M, int K) {
  __shared__ float As[32][68];
  __shared__ float Bs[32][68];
  const int tid = threadIdx.x;
  const int tx = tid & 15, ty = tid >> 4;
  const int n0 = blockIdx.x * 64, m0 = blockIdx.y * 64;
  float acc[4][4] = {};
  for (int k0 = 0; k0 < K; k0 += 32) {
#pragma unroll
    for (int l = 0; l < 2; ++l) {
      const int idx = tid + l * 256;
      const int row = idx >> 3;
      const int col = (idx & 7) << 2;
      const float4 av = *(const float4*)&A[(size_t)(n0 + row) * K + k0 + col];
      As[col + 0][row] = av.x; As[col + 1][row] = av.y;
      As[col + 2][row] = av.z; As[col + 3][row] = av.w;
      const float4 bv = *(const float4*)&Bm[(size_t)(m0 + row) * K + k0 + col];
      Bs[col + 0][row] = bv.x; Bs[col + 1][row] = bv.y;
      Bs[col + 2][row] = bv.z; Bs[col + 3][row] = bv.w;
    }
    __syncthreads();
#pragma unroll
    for (int k = 0; k < 32; ++k) {
      float a[4], bb[4];
      *(float4*)a  = *(const float4*)&As[k][ty * 4];
      *(float4*)bb = *(const float4*)&Bs[k][tx * 4];
#pragma unroll
      for (int i = 0; i < 4; ++i)
#pragma unroll
        for (int j = 0; j < 4; ++j) acc[i][j] = fmaf(a[i], bb[j], acc[i][j]);
    }
    __syncthreads();
  }
#pragma unroll
  for (int i = 0; i < 4; ++i) {
    const size_t n = n0 + ty * 4 + i;
#pragma unroll
    for (int j = 0; j < 4; ++j) {
      const int m = m0 + tx * 4 + j;
      const float val = acc[i][j] + (bias ? bias[m] : 0.f);
      if (OUT_BF16) ((__hip_bfloat16*)Cout)[n * M + m] = __float2bfloat16(val);
      else          ((float*)Cout)[n * M + m] = val;
    }
  }
}

extern "C" void kernel_launch(void* const* d_in, const int* in_sizes, int n_in,
                              void* d_out, int out_size, void* d_ws, size_t ws_size,
                              hipStream_t stream) {
  const float* x     = (const float*)d_in[0];
  const float* Win0  = (const float*)d_in[1];
  const float* Wrec0 = (const float*)d_in[2];
  const float* b0    = (const float*)d_in[3];
  const float* Win1  = (const float*)d_in[4];
  const float* Wrec1 = (const float*)d_in[5];
  const float* b1    = (const float*)d_in[6];
  const float* Wout  = (const float*)d_in[7];
  const float* bout  = (const float*)d_in[8];

  float* out     = (float*)d_out;
  float* states0 = out + (size_t)Bsz * Tlen * DOUT;
  float* states1 = states0 + (size_t)Bsz * Tlen * Hdim;

  unsigned* bar = (unsigned*)d_ws;  // root at [0]; 32 leaves at [32 + 32*i]
  __hip_bfloat16* X0 = (__hip_bfloat16*)((char*)d_ws + 16384);
  const size_t need = 16384 + (size_t)Bsz * Tlen * Hdim * sizeof(__hip_bfloat16);
  if (ws_size < need) return;

  hipMemsetAsync(d_ws, 0, 16384, stream);  // zero barrier counters

  // X0[b*T+t, h] = x[b,t,:] @ W_in0^T + b0   (bf16, hoisted out of the scan)
  gemm_nt<true><<<dim3((Bsz * Tlen) / 64, Hdim / 64), 256, 0, stream>>>(
      x, Win0, b0, (void*)X0, Bsz * Tlen, Hdim, DIN);

  // dyn-LDS: L1 weights 16*1024*4 = 65536B + partials 512*17*4 = 34816B
  //        = 100352B  (> 81920 -> still forces 1 block/CU)
  const int lds_bytes = 16 * 1024 * 4 + NTHR * PROW * 4;
  hipFuncSetAttribute((const void*)rnn_recurrent,
                      hipFuncAttributeMaxDynamicSharedMemorySize, lds_bytes);
  rnn_recurrent<<<NBLK, NTHR, lds_bytes, stream>>>(
      Wrec0, Wrec1, Win1, b1, X0, states0, states1, bar);

  // output = states1 @ W_out^T + b_out
  gemm_nt<false><<<dim3((Bsz * Tlen) / 64, DOUT / 64), 256, 0, stream>>>(
      states1, Wout, bout, (void*)out, Bsz * Tlen, DOUT, Hdim);
}

// Round 3
// 22388.890 us; speedup vs baseline: 2.0274x; 2.0274x over previous
//
#include <hip/hip_runtime.h>
#include <hip/hip_bf16.h>

// Leaky 2-layer CTRNN, B=64 T=512 D_IN=256 H=1024 D_OUT=256, alpha=0.1.
// Round 5: de-arrayified register tile (rule #20 fix).
//  Rounds 3/4 spilled ~190 dwords/thread/phase (WRITE_SIZE 50GB, VGPR pinned
//  at exactly 128 even with launch_bounds(512,2)): the v2f acc[4][8] array,
//  passed by reference into dot_tile/fold_scatter, defeated SROA (runtime
//  bi/hi indices at SROA time) -> alloca stayed in scratch -> every FMA was a
//  private-memory RMW. Fix: the 4h x 8b accumulator tile is now 32 NAMED v2f
//  locals (a00..a37) built by macros; dot/fold are macros over those names,
//  so every access is a static identifier. Live set ~110 VGPR, fits under
//  either 128 or 256 cap. Everything else identical to rounds 3/4:
//   - thread tile = 4h x 8b over a 32-wide interleaved k-slice
//   - w rows XOR-swizzled (c16 ^ ((c16>>3)&7)); measured ~0 bank conflicts
//   - partials: in-wave fold (__shfl_xor 1) + [512][17] LDS scatter/gather
//   - owner mapping (h=tid&7, b=tid>>3), v-carry, agent-relaxed tree barrier.

using v2f = __attribute__((ext_vector_type(2))) float;

constexpr int Bsz = 64, Tlen = 512, DIN = 256, Hdim = 1024, DOUT = 256;
constexpr int NBLK = 256;           // persistent, 1 per CU
constexpr int NTHR = 512;           // 8 waves
constexpr int CH = 8;               // h rows per block
constexpr int TH = Tlen * Hdim;     // per-batch state stride (floats)
constexpr int PROW = 17;            // partial-buffer row stride (odd: bank-clean)

__device__ __forceinline__ void gbarrier(unsigned* bar, unsigned phase) {
  __builtin_amdgcn_s_waitcnt(0);            // every thread drains its sc1 stores
  __syncthreads();
  if (threadIdx.x == 0) {
    unsigned* leaf = bar + 32 + (blockIdx.x & 31) * 32;   // 128B-padded leaves
    unsigned old = __hip_atomic_fetch_add(leaf, 1u, __ATOMIC_RELAXED,
                                          __HIP_MEMORY_SCOPE_AGENT);
    if ((old & 7u) == 7u)                   // 8th arrival at this leaf this phase
      __hip_atomic_fetch_add(bar, 1u, __ATOMIC_RELAXED, __HIP_MEMORY_SCOPE_AGENT);
    while (__hip_atomic_load(bar, __ATOMIC_RELAXED, __HIP_MEMORY_SCOPE_AGENT) <
           phase * 32u)
      __builtin_amdgcn_s_sleep(4);
    __builtin_amdgcn_fence(__ATOMIC_ACQUIRE, "agent");  // one buffer_inv
  }
  __syncthreads();
}

// ---- macro-generated 4h x 8b register tile: NAMED accumulators only ----
#define FOR_BI(M) M(0) M(1) M(2) M(3) M(4) M(5) M(6) M(7)

#define DECL_ACC(bi)                                                   \
  v2f a0##bi = {0.f, 0.f}, a1##bi = {0.f, 0.f},                        \
      a2##bi = {0.f, 0.f}, a3##bi = {0.f, 0.f};

#define STEP(bi) {                                                     \
    const float4 fq = *(const float4*)(fp0 + (size_t)bi * TH);         \
    const v2f fxy = {fq.x, fq.y}, fzw = {fq.z, fq.w};                  \
    a0##bi = __builtin_elementwise_fma(w0xy, fxy, a0##bi);             \
    a0##bi = __builtin_elementwise_fma(w0zw, fzw, a0##bi);             \
    a1##bi = __builtin_elementwise_fma(w1xy, fxy, a1##bi);             \
    a1##bi = __builtin_elementwise_fma(w1zw, fzw, a1##bi);             \
    a2##bi = __builtin_elementwise_fma(w2xy, fxy, a2##bi);             \
    a2##bi = __builtin_elementwise_fma(w2zw, fzw, a2##bi);             \
    a3##bi = __builtin_elementwise_fma(w3xy, fxy, a3##bi);             \
    a3##bi = __builtin_elementwise_fma(w3zw, fzw, a3##bi);             \
  }

// one full dot over K=1024: k in {4*ks + 128*j + 0..3 : j=0..7}
#define DOT_TILE(wb, frp) {                                            \
    _Pragma("unroll")                                                  \
    for (int j = 0; j < 8; ++j) {                                      \
      const int c16 = ks + 32 * j;                                     \
      const int phys = c16 ^ ((c16 >> 3) & 7);                         \
      const float* wp = (wb) + phys * 4;                               \
      const float4 w0q = *(const float4*)(wp);                         \
      const float4 w1q = *(const float4*)(wp + 1024);                  \
      const float4 w2q = *(const float4*)(wp + 2048);                  \
      const float4 w3q = *(const float4*)(wp + 3072);                  \
      const v2f w0xy = {w0q.x, w0q.y}, w0zw = {w0q.z, w0q.w};          \
      const v2f w1xy = {w1q.x, w1q.y}, w1zw = {w1q.z, w1q.w};          \
      const v2f w2xy = {w2q.x, w2q.y}, w2zw = {w2q.z, w2q.w};          \
      const v2f w3xy = {w3q.x, w3q.y}, w3zw = {w3q.z, w3q.w};          \
      const float* fp0 = (frp) + 4 * ks + 128 * j;                     \
      FOR_BI(STEP)                                                     \
    }                                                                  \
  }

// fold ks pairs in-wave (DPP), scatter folded partials to [512][PROW] LDS
#define FOLD(bi) {                                                     \
    float* pr = smP + ((8 * bp + bi) * 8 + 4 * hp) * PROW + col;       \
    float s0 = a0##bi.x + a0##bi.y; s0 += __shfl_xor(s0, 1);           \
    float s1 = a1##bi.x + a1##bi.y; s1 += __shfl_xor(s1, 1);           \
    float s2 = a2##bi.x + a2##bi.y; s2 += __shfl_xor(s2, 1);           \
    float s3 = a3##bi.x + a3##bi.y; s3 += __shfl_xor(s3, 1);           \
    if (wrp) {                                                         \
      pr[0 * PROW] = s0; pr[1 * PROW] = s1;                            \
      pr[2 * PROW] = s2; pr[3 * PROW] = s3;                            \
    }                                                                  \
  }

__device__ __forceinline__ float gather16(const float* __restrict__ prow) {
  float s0 = 0.f, s1 = 0.f, s2 = 0.f, s3 = 0.f;
#pragma unroll
  for (int c4 = 0; c4 < 16; c4 += 4) {
    s0 += prow[c4 + 0]; s1 += prow[c4 + 1];
    s2 += prow[c4 + 2]; s3 += prow[c4 + 3];
  }
  return (s0 + s1) + (s2 + s3);
}

__global__ void __launch_bounds__(NTHR, 2)
rnn_recurrent(const float* __restrict__ Wrec0, const float* __restrict__ Wrec1,
              const float* __restrict__ Win1,  const float* __restrict__ b1,
              const __hip_bfloat16* __restrict__ X0,
              float* __restrict__ states0, float* __restrict__ states1,
              unsigned* __restrict__ bar) {
  extern __shared__ float smW[];  // [nrows][1024] swizzled w, then [512][17] partials
  const int bid = blockIdx.x, tid = threadIdx.x;
  const bool isL1 = bid >= NBLK / 2;
  const int c = bid & (NBLK / 2 - 1);       // h chunk 0..127

  // ---- stage weights (swizzled by 16B chunk) ----
  const int nrows = isL1 ? 2 * CH : CH;
  for (int e = tid; e < nrows * 256; e += NTHR) {
    const int r = e >> 8, c16 = e & 255;
    const int phys = c16 ^ ((c16 >> 3) & 7);
    const float* src;
    if (!isL1)      src = Wrec0 + (size_t)(c * CH + r) * Hdim;
    else if (r < CH) src = Wrec1 + (size_t)(c * CH + r) * Hdim;
    else             src = Win1 + (size_t)(c * CH + r - CH) * Hdim;
    *(float4*)(smW + r * 1024 + phys * 4) = *(const float4*)(src + c16 * 4);
  }
  float* smP = smW + nrows * 1024;

  // ---- compute-role coords: tile rows {4hp..4hp+3} x b {8bp..8bp+7},
  //      k-slice ks (32-wide, interleaved) ----
  const int ks = tid & 31, hp = (tid >> 5) & 1, bp = tid >> 6;
  const float* wA = smW + (4 * hp) * 1024;          // rec rows
  const float* wB = smW + (CH + 4 * hp) * 1024;     // in rows (L1)
  const float* recS = (isL1 ? states1 : states0) + (size_t)(8 * bp) * TH;
  const float* inS  = states0 + (size_t)(8 * bp) * TH;

  // ---- owner-role coords: thread owns output (h_off, b), row == tid ----
  const int h_off = tid & 7, b = tid >> 3;
  const int h = c * CH + h_off;
  const float bias1 = isL1 ? b1[h] : 0.f;
  float* wr = (isL1 ? states1 : states0) + (size_t)b * TH + h;
  const __hip_bfloat16* x0p = X0 + (size_t)b * TH + h;
  const float* prow = smP + tid * PROW;
  float v = 0.f;
  __syncthreads();

  unsigned phase = 1;
  for (int p = 0; p <= Tlen; ++p) {
    // ---- scatter phase ----
    if (!isL1) {
      if (p > 0 && p < Tlen) {
        FOR_BI(DECL_ACC)
        const float* frA = recS + (size_t)(p - 1) * Hdim;
        DOT_TILE(wA, frA)
        const bool wrp = (ks & 1) == 0;
        const int col = ks >> 1;
        FOR_BI(FOLD)
      }
    } else if (p >= 1) {
      const int t = p - 1;
      FOR_BI(DECL_ACC)
      if (t > 0) {
        const float* frA = recS + (size_t)(t - 1) * Hdim;
        DOT_TILE(wA, frA)
      }
      {
        const float* frB = inS + (size_t)t * Hdim;
        DOT_TILE(wB, frB)
      }
      const bool wrp = (ks & 1) == 0;
      const int col = ks >> 1;
      FOR_BI(FOLD)
    }
    __syncthreads();
    // ---- gather + v update + store ----
    if (!isL1) {
      if (p < Tlen) {
        const float dotv = (p > 0) ? gather16(prow) : 0.f;
        const float accv = __bfloat162float(x0p[(size_t)p * Hdim]) + dotv;
        v = 0.9f * v + 0.1f * accv;
        __hip_atomic_store(wr + (size_t)p * Hdim, fmaxf(v, 0.f),
                           __ATOMIC_RELAXED, __HIP_MEMORY_SCOPE_AGENT);
      }
    } else if (p >= 1) {
      const int t = p - 1;
      const float accv = bias1 + gather16(prow);
      v = 0.9f * v + 0.1f * accv;
      __hip_atomic_store(wr + (size_t)t * Hdim, fmaxf(v, 0.f),
                         __ATOMIC_RELAXED, __HIP_MEMORY_SCOPE_AGENT);
    }
    if (p < Tlen) { gbarrier(bar, phase); ++phase; }
  }
}

// C[n,m] = sum_k A[n,k]*Bm[m,k] + bias[m]; 64x64 tile, fp32, out fp32 or bf16
template <bool OUT_BF16>
__global__ void __launch_bounds__(256)
gemm_nt(const float* __restrict__ A, const float* __restrict__ Bm,
        const float* __restrict__ bias, void* __restrict__ Cout,
        int N, int M, int K) {
  __shared__ float As[32][68];
  __shared__ float Bs[32][68];
  const int tid = threadIdx.x;
  const int tx = tid & 15, ty = tid >> 4;
  const int n0 = blockIdx.x * 64, m0 = blockIdx.y * 64;
  float acc[4][4] = {};
  for (int k0 = 0; k0 < K; k0 += 32) {
#pragma unroll
    for (int l = 0; l < 2; ++l) {
      const int idx = tid + l * 256;
      const int row = idx >> 3;
      const int col = (idx & 7) << 2;
      const float4 av = *(const float4*)&A[(size_t)(n0 + row) * K + k0 + col];
      As[col + 0][row] = av.x; As[col + 1][row] = av.y;
      As[col + 2][row] = av.z; As[col + 3][row] = av.w;
      const float4 bv = *(const float4*)&Bm[(size_t)(m0 + row) * K + k0 + col];
      Bs[col + 0][row] = bv.x; Bs[col + 1][row] = bv.y;
      Bs[col + 2][row] = bv.z; Bs[col + 3][row] = bv.w;
    }
    __syncthreads();
#pragma unroll
    for (int k = 0; k < 32; ++k) {
      float a[4], bb[4];
      *(float4*)a  = *(const float4*)&As[k][ty * 4];
      *(float4*)bb = *(const float4*)&Bs[k][tx * 4];
#pragma unroll
      for (int i = 0; i < 4; ++i)
#pragma unroll
        for (int j = 0; j < 4; ++j) acc[i][j] = fmaf(a[i], bb[j], acc[i][j]);
    }
    __syncthreads();
  }
#pragma unroll
  for (int i = 0; i < 4; ++i) {
    const size_t n = n0 + ty * 4 + i;
#pragma unroll
    for (int j = 0; j < 4; ++j) {
      const int m = m0 + tx * 4 + j;
      const float val = acc[i][j] + (bias ? bias[m] : 0.f);
      if (OUT_BF16) ((__hip_bfloat16*)Cout)[n * M + m] = __float2bfloat16(val);
      else          ((float*)Cout)[n * M + m] = val;
    }
  }
}

extern "C" void kernel_launch(void* const* d_in, const int* in_sizes, int n_in,
                              void* d_out, int out_size, void* d_ws, size_t ws_size,
                              hipStream_t stream) {
  const float* x     = (const float*)d_in[0];
  const float* Win0  = (const float*)d_in[1];
  const float* Wrec0 = (const float*)d_in[2];
  const float* b0    = (const float*)d_in[3];
  const float* Win1  = (const float*)d_in[4];
  const float* Wrec1 = (const float*)d_in[5];
  const float* b1    = (const float*)d_in[6];
  const float* Wout  = (const float*)d_in[7];
  const float* bout  = (const float*)d_in[8];

  float* out     = (float*)d_out;
  float* states0 = out + (size_t)Bsz * Tlen * DOUT;
  float* states1 = states0 + (size_t)Bsz * Tlen * Hdim;

  unsigned* bar = (unsigned*)d_ws;  // root at [0]; 32 leaves at [32 + 32*i]
  __hip_bfloat16* X0 = (__hip_bfloat16*)((char*)d_ws + 16384);
  const size_t need = 16384 + (size_t)Bsz * Tlen * Hdim * sizeof(__hip_bfloat16);
  if (ws_size < need) return;

  hipMemsetAsync(d_ws, 0, 16384, stream);  // zero barrier counters

  // X0[b*T+t, h] = x[b,t,:] @ W_in0^T + b0   (bf16, hoisted out of the scan)
  gemm_nt<true><<<dim3((Bsz * Tlen) / 64, Hdim / 64), 256, 0, stream>>>(
      x, Win0, b0, (void*)X0, Bsz * Tlen, Hdim, DIN);

  // dyn-LDS: L1 weights 16*1024*4 = 65536B + partials 512*17*4 = 34816B
  //        = 100352B  (> 81920 -> still forces 1 block/CU)
  const int lds_bytes = 16 * 1024 * 4 + NTHR * PROW * 4;
  hipFuncSetAttribute((const void*)rnn_recurrent,
                      hipFuncAttributeMaxDynamicSharedMemorySize, lds_bytes);
  rnn_recurrent<<<NBLK, NTHR, lds_bytes, stream>>>(
      Wrec0, Wrec1, Win1, b1, X0, states0, states1, bar);

  // output = states1 @ W_out^T + b_out
  gemm_nt<false><<<dim3((Bsz * Tlen) / 64, DOUT / 64), 256, 0, stream>>>(
      states1, Wout, bout, (void*)out, Bsz * Tlen, DOUT, Hdim);
}